// Round 13
// baseline (872.720 us; speedup 1.0000x reference)
//
#include <hip/hip_runtime.h>
#include <stdint.h>

using u16 = unsigned short;
typedef __bf16 bf16x8 __attribute__((ext_vector_type(8)));
typedef float f32x4 __attribute__((ext_vector_type(4)));
typedef u16 ushort8 __attribute__((ext_vector_type(8)));
typedef unsigned uint4v __attribute__((ext_vector_type(4)));
typedef unsigned uint2v __attribute__((ext_vector_type(2)));

// ===== session ledger (do not violate) =====
// attn_kernel on this toolchain:
//  - NO __builtin_amdgcn_s_setprio around MFMA (R5/R7: absmax 2.6e28)
//  - NO __launch_bounds__ second arg (R4/R11/R12: three bodies, all corrupt)
//  - NO v_permlane16_swap (R10: wrong lane routing)
//  - keep the R1-proven permlane32+shfl_xor xform and default VGPR heuristic
// ===========================================

__device__ __forceinline__ u16 f2bf(float f) {
    unsigned u = __builtin_bit_cast(unsigned, f);
    return (u16)((u + 0x7fffu + ((u >> 16) & 1u)) >> 16);
}

__device__ __forceinline__ float bf2f(u16 v) {
    unsigned u = (unsigned)v << 16;
    return __builtin_bit_cast(float, u);
}

__device__ __forceinline__ float fexp2(float x) {
#if __has_builtin(__builtin_amdgcn_exp2f)
    return __builtin_amdgcn_exp2f(x);
#else
    return exp2f(x);
#endif
}

__device__ __forceinline__ unsigned cvt_pk_bf16(float lo, float hi) {
    unsigned r;
    asm("v_cvt_pk_bf16_f32 %0, %1, %2" : "=v"(r) : "v"(lo), "v"(hi));
    return r;
}

// global->LDS direct copy, 16B per lane. LDS dest is wave-uniform base + lane*16.
#define GLD16(gptr, lptr) __builtin_amdgcn_global_load_lds( \
    (const __attribute__((address_space(1))) void*)(unsigned long long)(gptr), \
    (__attribute__((address_space(3))) void*)(unsigned)(unsigned long long)(lptr), 16, 0, 0)

// ---------------- conversion kernels ----------------

__global__ void convert_bf16(const float* __restrict__ in, u16* __restrict__ out) {
    int gid = blockIdx.x * 256 + threadIdx.x;      // 8 f32 per thread
    const float4* in4 = (const float4*)in;
    float4 a = in4[2 * gid], b = in4[2 * gid + 1];
    ushort8 o;
    o[0] = f2bf(a.x); o[1] = f2bf(a.y); o[2] = f2bf(a.z); o[3] = f2bf(a.w);
    o[4] = f2bf(b.x); o[5] = f2bf(b.y); o[6] = f2bf(b.z); o[7] = f2bf(b.w);
    *(ushort8*)(out + (size_t)gid * 8) = o;
}

// out[C][R] = bf16(in[R][C])  -- 64x64 LDS tile transpose
__global__ void transpose_convert(const float* __restrict__ in, u16* __restrict__ out,
                                  int R, int C) {
    __shared__ u16 sT[64][65];
    const int c0 = blockIdx.x << 6, r0 = blockIdx.y << 6;
    const int tid = threadIdx.x;
#pragma unroll
    for (int rep = 0; rep < 16; rep++) {
        int idx = rep * 256 + tid;
        int r = idx >> 6, c = idx & 63;
        sT[c][r] = f2bf(in[(size_t)(r0 + r) * C + c0 + c]);
    }
    __syncthreads();
#pragma unroll
    for (int rep = 0; rep < 16; rep++) {
        int idx = rep * 256 + tid;
        int r = idx >> 6, c = idx & 63;
        out[(size_t)(c0 + r) * R + r0 + c] = sT[r][c];
    }
}

// maskbits[i][w] bit (j&31) = (mask[i][2j+1] != 0), j = resized col index
__global__ void mask_pack(const float* __restrict__ mask, unsigned* __restrict__ mw) {
    int gid = blockIdx.x * 256 + threadIdx.x;      // 4096*2048 threads
    int i = gid >> 11, j = gid & 2047;
    float v = mask[(size_t)i * 4096 + 2 * j + 1];
    unsigned long long b = __ballot(v != 0.0f);
    int lane = threadIdx.x & 63;
    if (lane == 0)       mw[(size_t)i * 64 + (j >> 5)] = (unsigned)b;
    else if (lane == 32) mw[(size_t)i * 64 + (j >> 5)] = (unsigned)(b >> 32);
}

// ---------------- NT GEMM: C[i][j] = sum_k A[i][k]*B[j][k] ----------------
// A [M][K] row-major bf16, B [N][K] row-major bf16. 128x128 tile, BK=32, dbuf LDS.
// grid = (N/128, M/128, batches)

template <bool OUT_BF16, bool ADD_BIAS>
__global__ __launch_bounds__(256) void gemm_nt(
    const u16* __restrict__ A, int lda, long long sA,
    const u16* __restrict__ B, int ldb, long long sB,
    void* __restrict__ Cp, int ldc, long long sC,
    const float* __restrict__ bias, int K) {
    __shared__ __align__(16) u16 lds[2][2][4][128][8];   // [buf][mat][kblk][row][8] = 32KB
    const int bz = blockIdx.z;
    const u16* Ab = A + (size_t)sA * bz;
    const u16* Bb = B + (size_t)sB * bz;
    const int m0 = blockIdx.y << 7, n0 = blockIdx.x << 7;
    const int tid = threadIdx.x, wave = tid >> 6, lane = tid & 63;
    const int kg = lane >> 4, lr = lane & 15;
    const int wr = (wave >> 1) << 6, wc = (wave & 1) << 6;
    const int nT = K >> 5;
    f32x4 acc[4][4] = {};

    // prologue: stage tile 0 into buf 0. wave stages kblk==wave, rows i*64+lane.
#pragma unroll
    for (int i = 0; i < 2; i++) {
        int row = i * 64 + lane;
        GLD16(Ab + (size_t)(m0 + row) * lda + wave * 8, &lds[0][0][wave][i * 64][0]);
        GLD16(Bb + (size_t)(n0 + row) * ldb + wave * 8, &lds[0][1][wave][i * 64][0]);
    }
    for (int t = 0; t < nT; ++t) {
        const int cur = t & 1;
        if (t + 1 < nT) {
            const int nxt = cur ^ 1;
            const int koff = (t + 1) << 5;
#pragma unroll
            for (int i = 0; i < 2; i++) {
                int row = i * 64 + lane;
                GLD16(Ab + (size_t)(m0 + row) * lda + koff + wave * 8, &lds[nxt][0][wave][i * 64][0]);
                GLD16(Bb + (size_t)(n0 + row) * ldb + koff + wave * 8, &lds[nxt][1][wave][i * 64][0]);
            }
        }
        __syncthreads();   // drains vmcnt -> buf[cur] ready
        bf16x8 af[4], bfv[4];
#pragma unroll
        for (int mi = 0; mi < 4; mi++)
            af[mi] = *(const bf16x8*)&lds[cur][0][kg][wr + mi * 16 + lr][0];
#pragma unroll
        for (int ni = 0; ni < 4; ni++)
            bfv[ni] = *(const bf16x8*)&lds[cur][1][kg][wc + ni * 16 + lr][0];
#pragma unroll
        for (int mi = 0; mi < 4; mi++)
#pragma unroll
            for (int ni = 0; ni < 4; ni++)
                acc[mi][ni] = __builtin_amdgcn_mfma_f32_16x16x32_bf16(af[mi], bfv[ni], acc[mi][ni], 0, 0, 0);
        __syncthreads();   // all reads of buf[cur] done before it is re-staged
    }

    if constexpr (OUT_BF16) {
        u16* C = (u16*)Cp + (size_t)sC * bz;
#pragma unroll
        for (int mi = 0; mi < 4; mi++)
#pragma unroll
            for (int ni = 0; ni < 4; ni++)
#pragma unroll
                for (int r = 0; r < 4; r++) {
                    int gr = m0 + wr + mi * 16 + kg * 4 + r;
                    int gc = n0 + wc + ni * 16 + lr;
                    C[(size_t)gr * ldc + gc] = f2bf(acc[mi][ni][r]);
                }
    } else {
        float* C = (float*)Cp + (size_t)sC * bz;
#pragma unroll
        for (int mi = 0; mi < 4; mi++)
#pragma unroll
            for (int ni = 0; ni < 4; ni++)
#pragma unroll
                for (int r = 0; r < 4; r++) {
                    int gr = m0 + wr + mi * 16 + kg * 4 + r;
                    int gc = n0 + wc + ni * 16 + lr;
                    float v = acc[mi][ni][r];
                    if constexpr (ADD_BIAS) v += bias[gc];
                    C[(size_t)gr * ldc + gc] = v;
                }
    }
}

// ---- split-K variant: bz in [0,4) = (bsel = bz>>1, ks = bz&1). bf16 partials.
// Cpart[bz][i][j] = sum_{k in half ks} A[bsel-slice][i][k] * B[bsel-slice][j][k]
__global__ __launch_bounds__(256) void gemm_nt_splitk(
    const u16* __restrict__ A, int lda, long long sAb,
    const u16* __restrict__ B, int ldb, long long sBb,
    u16* __restrict__ Cp, int ldc, long long sC, int K2) {
    __shared__ __align__(16) u16 lds[2][2][4][128][8];
    const int bz = blockIdx.z, bsel = bz >> 1, ks = bz & 1;
    const u16* Ab = A + (size_t)sAb * bsel + (size_t)ks * K2;
    const u16* Bb = B + (size_t)sBb * bsel + (size_t)ks * K2;
    const int m0 = blockIdx.y << 7, n0 = blockIdx.x << 7;
    const int tid = threadIdx.x, wave = tid >> 6, lane = tid & 63;
    const int kg = lane >> 4, lr = lane & 15;
    const int wr = (wave >> 1) << 6, wc = (wave & 1) << 6;
    const int nT = K2 >> 5;
    f32x4 acc[4][4] = {};

#pragma unroll
    for (int i = 0; i < 2; i++) {
        int row = i * 64 + lane;
        GLD16(Ab + (size_t)(m0 + row) * lda + wave * 8, &lds[0][0][wave][i * 64][0]);
        GLD16(Bb + (size_t)(n0 + row) * ldb + wave * 8, &lds[0][1][wave][i * 64][0]);
    }
    for (int t = 0; t < nT; ++t) {
        const int cur = t & 1;
        if (t + 1 < nT) {
            const int nxt = cur ^ 1;
            const int koff = (t + 1) << 5;
#pragma unroll
            for (int i = 0; i < 2; i++) {
                int row = i * 64 + lane;
                GLD16(Ab + (size_t)(m0 + row) * lda + koff + wave * 8, &lds[nxt][0][wave][i * 64][0]);
                GLD16(Bb + (size_t)(n0 + row) * ldb + koff + wave * 8, &lds[nxt][1][wave][i * 64][0]);
            }
        }
        __syncthreads();
        bf16x8 af[4], bfv[4];
#pragma unroll
        for (int mi = 0; mi < 4; mi++)
            af[mi] = *(const bf16x8*)&lds[cur][0][kg][wr + mi * 16 + lr][0];
#pragma unroll
        for (int ni = 0; ni < 4; ni++)
            bfv[ni] = *(const bf16x8*)&lds[cur][1][kg][wc + ni * 16 + lr][0];
#pragma unroll
        for (int mi = 0; mi < 4; mi++)
#pragma unroll
            for (int ni = 0; ni < 4; ni++)
                acc[mi][ni] = __builtin_amdgcn_mfma_f32_16x16x32_bf16(af[mi], bfv[ni], acc[mi][ni], 0, 0, 0);
        __syncthreads();
    }

    u16* C = Cp + (size_t)sC * bz;
#pragma unroll
    for (int mi = 0; mi < 4; mi++)
#pragma unroll
        for (int ni = 0; ni < 4; ni++)
#pragma unroll
            for (int r = 0; r < 4; r++) {
                int gr = m0 + wr + mi * 16 + kg * 4 + r;
                int gc = n0 + wc + ni * 16 + lr;
                C[(size_t)gr * ldc + gc] = f2bf(acc[mi][ni][r]);
            }
}

// dst[d] = bf16( p[(2b)S + r] + p[(2b+1)S + r] ),  d = b*S + r, S = 2^21
__global__ void combine_bf16(const u16* __restrict__ p, u16* __restrict__ dst) {
    int gid = blockIdx.x * 256 + threadIdx.x;   // 524288 threads, 8 elems each
    size_t d = (size_t)gid * 8;
    size_t b = d >> 21, r = d & (((size_t)1 << 21) - 1);
    const ushort8 a = *(const ushort8*)(p + ((b * 2) << 21) + r);
    const ushort8 c = *(const ushort8*)(p + ((b * 2 + 1) << 21) + r);
    ushort8 o;
#pragma unroll
    for (int i = 0; i < 8; i++) o[i] = f2bf(bf2f(a[i]) + bf2f(c[i]));
    *(ushort8*)(dst + d) = o;
}

// ---------------- flash attention over compressed K/V (R9-exact, green) -------
// Per wave: 16 q rows (q = nrow+lr), loop kp tiles of 32.
// QK^T computed as S^T = mfma(K, Q): lane (kg,lr) holds S[kp=j0+kg*4+r][q=nrow+lr]
// (and +16 in s1). No max subtraction (scores ~N(0,1)); per-lane deferred sum.
// P -> PV B-frag via cvt_pk_bf16 + permlane32_swap + shfl_xor(16): no LDS at all.
// PV computed as O^T = mfma(V^T, P^T): lane holds O[q=lr][dh=f*16+kg*4+r].
// Grid is (bh=32, qchunk=64): XCD = bh%8, each XCD serves 4 heads = 2MB K/V (L2).

struct Frags {
    bf16x8 k0a, k0b, k1a, k1b;   // K rows j0+lr (cols kg*8, kg*8+32), j0+16+lr
    bf16x8 v0, v1, v2, v3;       // V^T rows f*16+lr, cols j0+kg*8
    unsigned wd;                 // mask word for q-row (nrow+lr), kp block j0>>5
};

__global__ __launch_bounds__(256) void attn_kernel(
    const u16* __restrict__ q, const u16* __restrict__ kb,
    const u16* __restrict__ vt, const unsigned* __restrict__ mw,
    u16* __restrict__ ao) {
    const int tid = threadIdx.x;
    const int wave = tid >> 6, lane = tid & 63, kg = lane >> 4, lr = lane & 15;
    const int b = blockIdx.x >> 4, h = blockIdx.x & 15;
    const int nrow = (blockIdx.y << 6) + wave * 16;

    const u16* qrow = q + (size_t)(b * 4096 + nrow + lr) * 1024 + h * 64 + kg * 8;
    const bf16x8 aq0 = *(const bf16x8*)qrow;
    const bf16x8 aq1 = *(const bf16x8*)(qrow + 32);
    const u16* kh = kb + (size_t)b * 2048 * 1024 + h * 64;
    const u16* vh = vt + ((size_t)b * 1024 + (size_t)h * 64) * 2048;
    const unsigned* mrow = mw + (size_t)(nrow + lr) * 64;

    f32x4 o[4] = {};      // o[f][r] = O[q=lr][dh = f*16 + kg*4 + r] (unnormalized)
    float lsum = 0.0f;
    const bool low16 = (lane & 16) == 0;

    auto tload = [&](Frags& S, int j0) {
        const u16* kr = kh + (size_t)(j0 + lr) * 1024 + kg * 8;
        S.k0a = *(const bf16x8*)kr;
        S.k0b = *(const bf16x8*)(kr + 32);
        S.k1a = *(const bf16x8*)(kr + 16 * 1024);
        S.k1b = *(const bf16x8*)(kr + 16 * 1024 + 32);
        const u16* vr = vh + (size_t)lr * 2048 + j0 + kg * 8;
        S.v0 = *(const bf16x8*)vr;
        S.v1 = *(const bf16x8*)(vr + 16 * 2048);
        S.v2 = *(const bf16x8*)(vr + 32 * 2048);
        S.v3 = *(const bf16x8*)(vr + 48 * 2048);
        S.wd = mrow[j0 >> 5];
    };

    auto process = [&](const Frags& S) {
        f32x4 s0 = {0.f, 0.f, 0.f, 0.f}, s1 = {0.f, 0.f, 0.f, 0.f};
        s0 = __builtin_amdgcn_mfma_f32_16x16x32_bf16(S.k0a, aq0, s0, 0, 0, 0);
        s0 = __builtin_amdgcn_mfma_f32_16x16x32_bf16(S.k0b, aq1, s0, 0, 0, 0);
        s1 = __builtin_amdgcn_mfma_f32_16x16x32_bf16(S.k1a, aq0, s1, 0, 0, 0);
        s1 = __builtin_amdgcn_mfma_f32_16x16x32_bf16(S.k1b, aq1, s1, 0, 0, 0);
        const unsigned mb0 = S.wd >> (kg * 4);
        const unsigned mb1 = S.wd >> (16 + kg * 4);
        // p = exp2(s * (0.125*log2e)); masked -> 0
        const float C = 0.18033688f;
        float p0[4], p1[4];
#pragma unroll
        for (int r = 0; r < 4; r++) {
            float t0 = ((mb0 >> r) & 1u) ? -1.0e30f : s0[r] * C;
            float t1 = ((mb1 >> r) & 1u) ? -1.0e30f : s1[r] * C;
            p0[r] = fexp2(t0);
            p1[r] = fexp2(t1);
            lsum += p0[r] + p1[r];
        }
        // pack to bf16 pairs: c* hold kp kg*4+{01,23}, d* hold kp 16+kg*4+{01,23}
        unsigned X0 = cvt_pk_bf16(p0[0], p0[1]);
        unsigned X1 = cvt_pk_bf16(p0[2], p0[3]);
        unsigned Y0 = cvt_pk_bf16(p1[0], p1[1]);
        unsigned Y1 = cvt_pk_bf16(p1[2], p1[3]);
        // lane-transpose P^T -> B-frag (lane needs kp slice kg*8..kg*8+7 for q=lr)
        asm volatile("v_permlane32_swap_b32 %0, %1" : "+v"(X0), "+v"(Y0));
        asm volatile("v_permlane32_swap_b32 %0, %1" : "+v"(X1), "+v"(Y1));
        unsigned sX0 = (unsigned)__shfl_xor((int)X0, 16);
        unsigned sY0 = (unsigned)__shfl_xor((int)Y0, 16);
        unsigned sX1 = (unsigned)__shfl_xor((int)X1, 16);
        unsigned sY1 = (unsigned)__shfl_xor((int)Y1, 16);
        uint4v wv;
        wv[0] = low16 ? X0 : sY0;
        wv[1] = low16 ? X1 : sY1;
        wv[2] = low16 ? sX0 : Y0;
        wv[3] = low16 ? sX1 : Y1;
        bf16x8 W = __builtin_bit_cast(bf16x8, wv);
        o[0] = __builtin_amdgcn_mfma_f32_16x16x32_bf16(S.v0, W, o[0], 0, 0, 0);
        o[1] = __builtin_amdgcn_mfma_f32_16x16x32_bf16(S.v1, W, o[1], 0, 0, 0);
        o[2] = __builtin_amdgcn_mfma_f32_16x16x32_bf16(S.v2, W, o[2], 0, 0, 0);
        o[3] = __builtin_amdgcn_mfma_f32_16x16x32_bf16(S.v3, W, o[3], 0, 0, 0);
    };

    Frags A, B;
    tload(A, 0);
    for (int t = 0; t < 62; t += 2) {
        tload(B, (t + 1) * 32);
        process(A);
        tload(A, (t + 2) * 32);
        process(B);
    }
    tload(B, 63 * 32);
    process(A);
    process(B);

    lsum += __shfl_xor(lsum, 16);
    lsum += __shfl_xor(lsum, 32);
    const float inv = 1.0f / lsum;

    u16* orow = ao + (size_t)(b * 4096 + nrow + lr) * 1024 + h * 64 + kg * 4;
#pragma unroll
    for (int f = 0; f < 4; f++) {
        uint2v st;
        st[0] = cvt_pk_bf16(o[f][0] * inv, o[f][1] * inv);
        st[1] = cvt_pk_bf16(o[f][2] * inv, o[f][3] * inv);
        *(uint2v*)(orow + f * 16) = st;
    }
}

// ---------------- launcher ----------------

extern "C" void kernel_launch(void* const* d_in, const int* in_sizes, int n_in,
                              void* d_out, int out_size, void* d_ws, size_t ws_size,
                              hipStream_t stream) {
    const float* x    = (const float*)d_in[0];
    const float* mask = (const float*)d_in[1];
    const float* Wq   = (const float*)d_in[2];
    const float* Wk   = (const float*)d_in[3];
    const float* Wv   = (const float*)d_in[4];
    const float* Wo   = (const float*)d_in[5];
    const float* bo   = (const float*)d_in[6];
    const float* pk   = (const float*)d_in[7];
    const float* pv   = (const float*)d_in[8];
    float* out = (float*)d_out;

    char* w = (char*)d_ws;
    auto alloc = [&](size_t bytes) { void* p = w; w += (bytes + 255) & ~(size_t)255; return p; };
    u16* xb   = (u16*)alloc((size_t)8192 * 1024 * 2);
    u16* qb   = (u16*)alloc((size_t)8192 * 1024 * 2);
    u16* xkT  = (u16*)alloc((size_t)1024 * 8192 * 2);   // [xkT|xvT] contiguous:
    u16* xvT  = (u16*)alloc((size_t)1024 * 8192 * 2);   // fused M=2048 GEMM output
    u16* WqT  = (u16*)alloc((size_t)1024 * 1024 * 2);
    u16* WkT  = (u16*)alloc((size_t)1024 * 1024 * 2);   // [WkT|WvT] contiguous:
    u16* WvT  = (u16*)alloc((size_t)1024 * 1024 * 2);   // fused GEMM A-operand
    u16* WoT  = (u16*)alloc((size_t)1024 * 1024 * 2);
    u16* pkT  = (u16*)alloc((size_t)2048 * 4096 * 2);
    u16* pvT  = (u16*)alloc((size_t)2048 * 4096 * 2);
    u16* kbuf = (u16*)alloc((size_t)2 * 2048 * 1024 * 2);
    u16* vtb  = (u16*)alloc((size_t)2 * 1024 * 2048 * 2);
    unsigned* mw = (unsigned*)alloc((size_t)4096 * 64 * 4);
    (void)alloc((size_t)128 * 1024);   // guard pad
    u16* ao   = xb;   // alias: xb dead after q-proj; attention writes after that
    u16* pbuf = qb;   // alias: 4 x 2048x1024 bf16 partials = 16MB, dead before q-proj
    (void)xvT;

    convert_bf16<<<4096, 256, 0, stream>>>(x, xb);
    transpose_convert<<<dim3(16, 16), 256, 0, stream>>>(Wq, WqT, 1024, 1024);
    transpose_convert<<<dim3(16, 16), 256, 0, stream>>>(Wk, WkT, 1024, 1024);
    transpose_convert<<<dim3(16, 16), 256, 0, stream>>>(Wv, WvT, 1024, 1024);
    transpose_convert<<<dim3(16, 16), 256, 0, stream>>>(Wo, WoT, 1024, 1024);
    transpose_convert<<<dim3(32, 64), 256, 0, stream>>>(pk, pkT, 4096, 2048);
    transpose_convert<<<dim3(32, 64), 256, 0, stream>>>(pv, pvT, 4096, 2048);
    mask_pack<<<32768, 256, 0, stream>>>(mask, mw);

    // fused [xkT|xvT] = [WkT|WvT](M=2048) x B(xb) : [2048,8192], one launch
    gemm_nt<true, false><<<dim3(64, 16, 1), 256, 0, stream>>>(WkT, 1024, 0, xb, 1024, 0, xkT, 8192, 0, nullptr, 1024);

    // k[b] = proj_k^T @ xk[b] : split-K x2 -> bf16 partials -> combine
    gemm_nt_splitk<<<dim3(8, 16, 4), 256, 0, stream>>>(pkT, 4096, 0, xkT, 8192, 4096,
                                                       pbuf, 1024, (long long)1 << 21, 2048);
    combine_bf16<<<2048, 256, 0, stream>>>(pbuf, kbuf);
    // vT[b] = xv[b]^T @ proj_v : split-K x2
    gemm_nt_splitk<<<dim3(16, 8, 4), 256, 0, stream>>>(xvT, 8192, 4096, pvT, 4096, 0,
                                                       pbuf, 2048, (long long)1 << 21, 2048);
    combine_bf16<<<2048, 256, 0, stream>>>(pbuf, vtb);

    // q = x @ Wq (runs AFTER combines: qb overlays pbuf)
    gemm_nt<true, false><<<dim3(8, 64, 1), 256, 0, stream>>>(xb, 1024, 0, WqT, 1024, 0, qb, 1024, 0, nullptr, 1024);

    // grid (bh, qchunk): consecutive blocks differ in bh -> XCD = bh%8 (L2 locality)
    attn_kernel<<<dim3(32, 64), 256, 0, stream>>>(qb, kbuf, vtb, mw, ao);

    // out = ao @ Wo + bo (f32 out)
    gemm_nt<false, true><<<dim3(8, 64, 1), 256, 0, stream>>>(ao, 1024, 0, WoT, 1024, 0, out, 1024, 0, bo, 1024);
}

// Round 14
// 567.278 us; speedup vs baseline: 1.5384x; 1.5384x over previous
//
#include <hip/hip_runtime.h>
#include <stdint.h>

using u16 = unsigned short;
typedef __bf16 bf16x8 __attribute__((ext_vector_type(8)));
typedef float f32x4 __attribute__((ext_vector_type(4)));
typedef u16 ushort8 __attribute__((ext_vector_type(8)));
typedef unsigned uint4v __attribute__((ext_vector_type(4)));
typedef unsigned uint2v __attribute__((ext_vector_type(2)));

// ===== session ledger (do not violate) =====
// attn_kernel on this toolchain:
//  - NO __builtin_amdgcn_s_setprio around MFMA (R5/R7: absmax 2.6e28)
//  - NO __launch_bounds__ second arg (R4/R11/R12: three bodies, all corrupt)
//  - NO v_permlane16_swap (R10: wrong lane routing)
//  - NO global_load_lds under wave-divergent branches (R2/R3 suspect; gemm's
//    branch-free wave-indexed staging is proven green 13 rounds)
// ===========================================

__device__ __forceinline__ u16 f2bf(float f) {
    unsigned u = __builtin_bit_cast(unsigned, f);
    return (u16)((u + 0x7fffu + ((u >> 16) & 1u)) >> 16);
}

__device__ __forceinline__ float bf2f(u16 v) {
    unsigned u = (unsigned)v << 16;
    return __builtin_bit_cast(float, u);
}

__device__ __forceinline__ float fexp2(float x) {
#if __has_builtin(__builtin_amdgcn_exp2f)
    return __builtin_amdgcn_exp2f(x);
#else
    return exp2f(x);
#endif
}

__device__ __forceinline__ unsigned cvt_pk_bf16(float lo, float hi) {
    unsigned r;
    asm("v_cvt_pk_bf16_f32 %0, %1, %2" : "=v"(r) : "v"(lo), "v"(hi));
    return r;
}

// global->LDS direct copy, 16B per lane. LDS dest is wave-uniform base + lane*16.
#define GLD16(gptr, lptr) __builtin_amdgcn_global_load_lds( \
    (const __attribute__((address_space(1))) void*)(unsigned long long)(gptr), \
    (__attribute__((address_space(3))) void*)(unsigned)(unsigned long long)(lptr), 16, 0, 0)

// ---------------- conversion kernels ----------------

__global__ void convert_bf16(const float* __restrict__ in, u16* __restrict__ out) {
    int gid = blockIdx.x * 256 + threadIdx.x;      // 8 f32 per thread
    const float4* in4 = (const float4*)in;
    float4 a = in4[2 * gid], b = in4[2 * gid + 1];
    ushort8 o;
    o[0] = f2bf(a.x); o[1] = f2bf(a.y); o[2] = f2bf(a.z); o[3] = f2bf(a.w);
    o[4] = f2bf(b.x); o[5] = f2bf(b.y); o[6] = f2bf(b.z); o[7] = f2bf(b.w);
    *(ushort8*)(out + (size_t)gid * 8) = o;
}

// out[C][R] = bf16(in[R][C])  -- 64x64 LDS tile transpose
__global__ void transpose_convert(const float* __restrict__ in, u16* __restrict__ out,
                                  int R, int C) {
    __shared__ u16 sT[64][65];
    const int c0 = blockIdx.x << 6, r0 = blockIdx.y << 6;
    const int tid = threadIdx.x;
#pragma unroll
    for (int rep = 0; rep < 16; rep++) {
        int idx = rep * 256 + tid;
        int r = idx >> 6, c = idx & 63;
        sT[c][r] = f2bf(in[(size_t)(r0 + r) * C + c0 + c]);
    }
    __syncthreads();
#pragma unroll
    for (int rep = 0; rep < 16; rep++) {
        int idx = rep * 256 + tid;
        int r = idx >> 6, c = idx & 63;
        out[(size_t)(c0 + r) * R + r0 + c] = sT[r][c];
    }
}

// maskbits[i][w] bit (j&31) = (mask[i][2j+1] != 0), j = resized col index
__global__ void mask_pack(const float* __restrict__ mask, unsigned* __restrict__ mw) {
    int gid = blockIdx.x * 256 + threadIdx.x;      // 4096*2048 threads
    int i = gid >> 11, j = gid & 2047;
    float v = mask[(size_t)i * 4096 + 2 * j + 1];
    unsigned long long b = __ballot(v != 0.0f);
    int lane = threadIdx.x & 63;
    if (lane == 0)       mw[(size_t)i * 64 + (j >> 5)] = (unsigned)b;
    else if (lane == 32) mw[(size_t)i * 64 + (j >> 5)] = (unsigned)(b >> 32);
}

// ---------------- NT GEMM: C[i][j] = sum_k A[i][k]*B[j][k] ----------------
// A [M][K] row-major bf16, B [N][K] row-major bf16. 128x128 tile, BK=32, dbuf LDS.
// grid = (N/128, M/128, batches)

template <bool OUT_BF16, bool ADD_BIAS>
__global__ __launch_bounds__(256) void gemm_nt(
    const u16* __restrict__ A, int lda, long long sA,
    const u16* __restrict__ B, int ldb, long long sB,
    void* __restrict__ Cp, int ldc, long long sC,
    const float* __restrict__ bias, int K) {
    __shared__ __align__(16) u16 lds[2][2][4][128][8];   // [buf][mat][kblk][row][8] = 32KB
    const int bz = blockIdx.z;
    const u16* Ab = A + (size_t)sA * bz;
    const u16* Bb = B + (size_t)sB * bz;
    const int m0 = blockIdx.y << 7, n0 = blockIdx.x << 7;
    const int tid = threadIdx.x, wave = tid >> 6, lane = tid & 63;
    const int kg = lane >> 4, lr = lane & 15;
    const int wr = (wave >> 1) << 6, wc = (wave & 1) << 6;
    const int nT = K >> 5;
    f32x4 acc[4][4] = {};

    // prologue: stage tile 0 into buf 0. wave stages kblk==wave, rows i*64+lane.
#pragma unroll
    for (int i = 0; i < 2; i++) {
        int row = i * 64 + lane;
        GLD16(Ab + (size_t)(m0 + row) * lda + wave * 8, &lds[0][0][wave][i * 64][0]);
        GLD16(Bb + (size_t)(n0 + row) * ldb + wave * 8, &lds[0][1][wave][i * 64][0]);
    }
    for (int t = 0; t < nT; ++t) {
        const int cur = t & 1;
        if (t + 1 < nT) {
            const int nxt = cur ^ 1;
            const int koff = (t + 1) << 5;
#pragma unroll
            for (int i = 0; i < 2; i++) {
                int row = i * 64 + lane;
                GLD16(Ab + (size_t)(m0 + row) * lda + koff + wave * 8, &lds[nxt][0][wave][i * 64][0]);
                GLD16(Bb + (size_t)(n0 + row) * ldb + koff + wave * 8, &lds[nxt][1][wave][i * 64][0]);
            }
        }
        __syncthreads();   // drains vmcnt -> buf[cur] ready
        bf16x8 af[4], bfv[4];
#pragma unroll
        for (int mi = 0; mi < 4; mi++)
            af[mi] = *(const bf16x8*)&lds[cur][0][kg][wr + mi * 16 + lr][0];
#pragma unroll
        for (int ni = 0; ni < 4; ni++)
            bfv[ni] = *(const bf16x8*)&lds[cur][1][kg][wc + ni * 16 + lr][0];
#pragma unroll
        for (int mi = 0; mi < 4; mi++)
#pragma unroll
            for (int ni = 0; ni < 4; ni++)
                acc[mi][ni] = __builtin_amdgcn_mfma_f32_16x16x32_bf16(af[mi], bfv[ni], acc[mi][ni], 0, 0, 0);
        __syncthreads();   // all reads of buf[cur] done before it is re-staged
    }

    if constexpr (OUT_BF16) {
        u16* C = (u16*)Cp + (size_t)sC * bz;
#pragma unroll
        for (int mi = 0; mi < 4; mi++)
#pragma unroll
            for (int ni = 0; ni < 4; ni++)
#pragma unroll
                for (int r = 0; r < 4; r++) {
                    int gr = m0 + wr + mi * 16 + kg * 4 + r;
                    int gc = n0 + wc + ni * 16 + lr;
                    C[(size_t)gr * ldc + gc] = f2bf(acc[mi][ni][r]);
                }
    } else {
        float* C = (float*)Cp + (size_t)sC * bz;
#pragma unroll
        for (int mi = 0; mi < 4; mi++)
#pragma unroll
            for (int ni = 0; ni < 4; ni++)
#pragma unroll
                for (int r = 0; r < 4; r++) {
                    int gr = m0 + wr + mi * 16 + kg * 4 + r;
                    int gc = n0 + wc + ni * 16 + lr;
                    float v = acc[mi][ni][r];
                    if constexpr (ADD_BIAS) v += bias[gc];
                    C[(size_t)gr * ldc + gc] = v;
                }
    }
}

// ---- split-K variant: bz in [0,4) = (bsel = bz>>1, ks = bz&1). bf16 partials.
// Cpart[bz][i][j] = sum_{k in half ks} A[bsel-slice][i][k] * B[bsel-slice][j][k]
__global__ __launch_bounds__(256) void gemm_nt_splitk(
    const u16* __restrict__ A, int lda, long long sAb,
    const u16* __restrict__ B, int ldb, long long sBb,
    u16* __restrict__ Cp, int ldc, long long sC, int K2) {
    __shared__ __align__(16) u16 lds[2][2][4][128][8];
    const int bz = blockIdx.z, bsel = bz >> 1, ks = bz & 1;
    const u16* Ab = A + (size_t)sAb * bsel + (size_t)ks * K2;
    const u16* Bb = B + (size_t)sBb * bsel + (size_t)ks * K2;
    const int m0 = blockIdx.y << 7, n0 = blockIdx.x << 7;
    const int tid = threadIdx.x, wave = tid >> 6, lane = tid & 63;
    const int kg = lane >> 4, lr = lane & 15;
    const int wr = (wave >> 1) << 6, wc = (wave & 1) << 6;
    const int nT = K2 >> 5;
    f32x4 acc[4][4] = {};

#pragma unroll
    for (int i = 0; i < 2; i++) {
        int row = i * 64 + lane;
        GLD16(Ab + (size_t)(m0 + row) * lda + wave * 8, &lds[0][0][wave][i * 64][0]);
        GLD16(Bb + (size_t)(n0 + row) * ldb + wave * 8, &lds[0][1][wave][i * 64][0]);
    }
    for (int t = 0; t < nT; ++t) {
        const int cur = t & 1;
        if (t + 1 < nT) {
            const int nxt = cur ^ 1;
            const int koff = (t + 1) << 5;
#pragma unroll
            for (int i = 0; i < 2; i++) {
                int row = i * 64 + lane;
                GLD16(Ab + (size_t)(m0 + row) * lda + koff + wave * 8, &lds[nxt][0][wave][i * 64][0]);
                GLD16(Bb + (size_t)(n0 + row) * ldb + koff + wave * 8, &lds[nxt][1][wave][i * 64][0]);
            }
        }
        __syncthreads();
        bf16x8 af[4], bfv[4];
#pragma unroll
        for (int mi = 0; mi < 4; mi++)
            af[mi] = *(const bf16x8*)&lds[cur][0][kg][wr + mi * 16 + lr][0];
#pragma unroll
        for (int ni = 0; ni < 4; ni++)
            bfv[ni] = *(const bf16x8*)&lds[cur][1][kg][wc + ni * 16 + lr][0];
#pragma unroll
        for (int mi = 0; mi < 4; mi++)
#pragma unroll
            for (int ni = 0; ni < 4; ni++)
                acc[mi][ni] = __builtin_amdgcn_mfma_f32_16x16x32_bf16(af[mi], bfv[ni], acc[mi][ni], 0, 0, 0);
        __syncthreads();
    }

    u16* C = Cp + (size_t)sC * bz;
#pragma unroll
    for (int mi = 0; mi < 4; mi++)
#pragma unroll
        for (int ni = 0; ni < 4; ni++)
#pragma unroll
            for (int r = 0; r < 4; r++) {
                int gr = m0 + wr + mi * 16 + kg * 4 + r;
                int gc = n0 + wc + ni * 16 + lr;
                C[(size_t)gr * ldc + gc] = f2bf(acc[mi][ni][r]);
            }
}

// dst[d] = bf16( p[(2b)S + r] + p[(2b+1)S + r] ),  d = b*S + r, S = 2^21
__global__ void combine_bf16(const u16* __restrict__ p, u16* __restrict__ dst) {
    int gid = blockIdx.x * 256 + threadIdx.x;   // 524288 threads, 8 elems each
    size_t d = (size_t)gid * 8;
    size_t b = d >> 21, r = d & (((size_t)1 << 21) - 1);
    const ushort8 a = *(const ushort8*)(p + ((b * 2) << 21) + r);
    const ushort8 c = *(const ushort8*)(p + ((b * 2 + 1) << 21) + r);
    ushort8 o;
#pragma unroll
    for (int i = 0; i < 8; i++) o[i] = f2bf(bf2f(a[i]) + bf2f(c[i]));
    *(ushort8*)(dst + d) = o;
}

// ---------------- flash attention over compressed K/V (LDS-staged v3) ---------
// Per wave: 16 q rows (q = nrow+lr), loop kp tiles of 32. Math/xform/stores are
// BYTE-IDENTICAL to the R13-green kernel; only the K/V byte source changes:
// per tile, the block stages K-tile [32 kp][64 dh] (4KB) and V^T-tile
// [64 dh][32 kp] (4KB) into dbuf LDS via the gemm-proven BRANCH-FREE pattern --
// every thread issues exactly 1 K-GLD16 + 1 V-GLD16, wave-indexed:
//   K: thread (w,l): dest [dh8=w*2+l/32][kp=l%32] = base(&sK[bf][w*2][0][0])+l*16
//      src  K[j0 + l%32][dh = (w*2+l/32)*8]
//   V: thread (w,l): dest [kp8=w][dh=l] = base(&sV[bf][w][0][0])+l*16
//      src  V^T[dh=l][j0 + w*8]
// Frag reads (verified == old tload values):
//   k0a=sK[kg][lr] k0b=sK[4+kg][lr] k1a=sK[kg][16+lr] k1b=sK[4+kg][16+lr]
//   v0..v3 = sV[kg][f*16+lr]
// Grid (bh=32, qchunk=64): XCD = bh%8 (L2 locality, R9-proven).

__global__ __launch_bounds__(256) void attn_kernel(
    const u16* __restrict__ q, const u16* __restrict__ kb,
    const u16* __restrict__ vt, const unsigned* __restrict__ mw,
    u16* __restrict__ ao) {
    __shared__ __align__(16) u16 sK[2][8][32][8];   // [buf][dh8][kp][8] 4KB/buf
    __shared__ __align__(16) u16 sV[2][4][64][8];   // [buf][kp8][dh][8] 4KB/buf
    const int tid = threadIdx.x;
    const int wave = tid >> 6, lane = tid & 63, kg = lane >> 4, lr = lane & 15;
    const int b = blockIdx.x >> 4, h = blockIdx.x & 15;
    const int nrow = (blockIdx.y << 6) + wave * 16;

    const u16* qrow = q + (size_t)(b * 4096 + nrow + lr) * 1024 + h * 64 + kg * 8;
    const bf16x8 aq0 = *(const bf16x8*)qrow;
    const bf16x8 aq1 = *(const bf16x8*)(qrow + 32);
    const u16* kh = kb + (size_t)b * 2048 * 1024 + h * 64;
    const u16* vh = vt + ((size_t)b * 1024 + (size_t)h * 64) * 2048;
    const unsigned* mrow = mw + (size_t)(nrow + lr) * 64;

    // branch-free staging addresses (fixed per thread; only j0 varies)
    const u16* ksrc = kh + (size_t)(lane & 31) * 1024 + (wave * 2 + (lane >> 5)) * 8;
    const u16* vsrc = vh + (size_t)lane * 2048 + wave * 8;

    f32x4 o[4] = {};      // o[f][r] = O[q=lr][dh = f*16 + kg*4 + r] (unnormalized)
    float lsum = 0.0f;
    const bool low16 = (lane & 16) == 0;

    auto stage = [&](int bf, int j0) {
        GLD16(ksrc + (size_t)j0 * 1024, &sK[bf][wave * 2][0][0]);
        GLD16(vsrc + j0, &sV[bf][wave][0][0]);
    };

    auto process = [&](int cur, unsigned wd) {
        const bf16x8 k0a = *(const bf16x8*)&sK[cur][kg][lr][0];
        const bf16x8 k0b = *(const bf16x8*)&sK[cur][4 + kg][lr][0];
        const bf16x8 k1a = *(const bf16x8*)&sK[cur][kg][16 + lr][0];
        const bf16x8 k1b = *(const bf16x8*)&sK[cur][4 + kg][16 + lr][0];
        const bf16x8 v0 = *(const bf16x8*)&sV[cur][kg][lr][0];
        const bf16x8 v1 = *(const bf16x8*)&sV[cur][kg][16 + lr][0];
        const bf16x8 v2 = *(const bf16x8*)&sV[cur][kg][32 + lr][0];
        const bf16x8 v3 = *(const bf16x8*)&sV[cur][kg][48 + lr][0];

        f32x4 s0 = {0.f, 0.f, 0.f, 0.f}, s1 = {0.f, 0.f, 0.f, 0.f};
        s0 = __builtin_amdgcn_mfma_f32_16x16x32_bf16(k0a, aq0, s0, 0, 0, 0);
        s0 = __builtin_amdgcn_mfma_f32_16x16x32_bf16(k0b, aq1, s0, 0, 0, 0);
        s1 = __builtin_amdgcn_mfma_f32_16x16x32_bf16(k1a, aq0, s1, 0, 0, 0);
        s1 = __builtin_amdgcn_mfma_f32_16x16x32_bf16(k1b, aq1, s1, 0, 0, 0);
        const unsigned mb0 = wd >> (kg * 4);
        const unsigned mb1 = wd >> (16 + kg * 4);
        // p = exp2(s * (0.125*log2e)); masked -> 0
        const float C = 0.18033688f;
        float p0[4], p1[4];
#pragma unroll
        for (int r = 0; r < 4; r++) {
            float t0 = ((mb0 >> r) & 1u) ? -1.0e30f : s0[r] * C;
            float t1 = ((mb1 >> r) & 1u) ? -1.0e30f : s1[r] * C;
            p0[r] = fexp2(t0);
            p1[r] = fexp2(t1);
            lsum += p0[r] + p1[r];
        }
        // pack to bf16 pairs: c* hold kp kg*4+{01,23}, d* hold kp 16+kg*4+{01,23}
        unsigned X0 = cvt_pk_bf16(p0[0], p0[1]);
        unsigned X1 = cvt_pk_bf16(p0[2], p0[3]);
        unsigned Y0 = cvt_pk_bf16(p1[0], p1[1]);
        unsigned Y1 = cvt_pk_bf16(p1[2], p1[3]);
        // lane-transpose P^T -> B-frag (lane needs kp slice kg*8..kg*8+7 for q=lr)
        asm volatile("v_permlane32_swap_b32 %0, %1" : "+v"(X0), "+v"(Y0));
        asm volatile("v_permlane32_swap_b32 %0, %1" : "+v"(X1), "+v"(Y1));
        unsigned sX0 = (unsigned)__shfl_xor((int)X0, 16);
        unsigned sY0 = (unsigned)__shfl_xor((int)Y0, 16);
        unsigned sX1 = (unsigned)__shfl_xor((int)X1, 16);
        unsigned sY1 = (unsigned)__shfl_xor((int)Y1, 16);
        uint4v wv;
        wv[0] = low16 ? X0 : sY0;
        wv[1] = low16 ? X1 : sY1;
        wv[2] = low16 ? sX0 : Y0;
        wv[3] = low16 ? sX1 : Y1;
        bf16x8 W = __builtin_bit_cast(bf16x8, wv);
        o[0] = __builtin_amdgcn_mfma_f32_16x16x32_bf16(v0, W, o[0], 0, 0, 0);
        o[1] = __builtin_amdgcn_mfma_f32_16x16x32_bf16(v1, W, o[1], 0, 0, 0);
        o[2] = __builtin_amdgcn_mfma_f32_16x16x32_bf16(v2, W, o[2], 0, 0, 0);
        o[3] = __builtin_amdgcn_mfma_f32_16x16x32_bf16(v3, W, o[3], 0, 0, 0);
    };

    stage(0, 0);
    for (int t = 0; t < 64; ++t) {
        const int cur = t & 1;
        if (t < 63) stage(cur ^ 1, (t + 1) * 32);
        __syncthreads();   // drains vmcnt -> buf[cur] ready
        process(cur, mrow[t]);
        __syncthreads();   // all reads of buf[cur] done before re-stage
    }

    lsum += __shfl_xor(lsum, 16);
    lsum += __shfl_xor(lsum, 32);
    const float inv = 1.0f / lsum;

    u16* orow = ao + (size_t)(b * 4096 + nrow + lr) * 1024 + h * 64 + kg * 4;
#pragma unroll
    for (int f = 0; f < 4; f++) {
        uint2v st;
        st[0] = cvt_pk_bf16(o[f][0] * inv, o[f][1] * inv);
        st[1] = cvt_pk_bf16(o[f][2] * inv, o[f][3] * inv);
        *(uint2v*)(orow + f * 16) = st;
    }
}

// ---------------- launcher ----------------

extern "C" void kernel_launch(void* const* d_in, const int* in_sizes, int n_in,
                              void* d_out, int out_size, void* d_ws, size_t ws_size,
                              hipStream_t stream) {
    const float* x    = (const float*)d_in[0];
    const float* mask = (const float*)d_in[1];
    const float* Wq   = (const float*)d_in[2];
    const float* Wk   = (const float*)d_in[3];
    const float* Wv   = (const float*)d_in[4];
    const float* Wo   = (const float*)d_in[5];
    const float* bo   = (const float*)d_in[6];
    const float* pk   = (const float*)d_in[7];
    const float* pv   = (const float*)d_in[8];
    float* out = (float*)d_out;

    char* w = (char*)d_ws;
    auto alloc = [&](size_t bytes) { void* p = w; w += (bytes + 255) & ~(size_t)255; return p; };
    u16* xb   = (u16*)alloc((size_t)8192 * 1024 * 2);
    u16* qb   = (u16*)alloc((size_t)8192 * 1024 * 2);
    u16* xkT  = (u16*)alloc((size_t)1024 * 8192 * 2);   // [xkT|xvT] contiguous:
    u16* xvT  = (u16*)alloc((size_t)1024 * 8192 * 2);   // fused M=2048 GEMM output
    u16* WqT  = (u16*)alloc((size_t)1024 * 1024 * 2);
    u16* WkT  = (u16*)alloc((size_t)1024 * 1024 * 2);   // [WkT|WvT] contiguous:
    u16* WvT  = (u16*)alloc((size_t)1024 * 1024 * 2);   // fused GEMM A-operand
    u16* WoT  = (u16*)alloc((size_t)1024 * 1024 * 2);
    u16* pkT  = (u16*)alloc((size_t)2048 * 4096 * 2);
    u16* pvT  = (u16*)alloc((size_t)2048 * 4096 * 2);
    u16* kbuf = (u16*)alloc((size_t)2 * 2048 * 1024 * 2);
    u16* vtb  = (u16*)alloc((size_t)2 * 1024 * 2048 * 2);
    unsigned* mw = (unsigned*)alloc((size_t)4096 * 64 * 4);
    (void)alloc((size_t)128 * 1024);   // guard pad
    u16* ao   = xb;   // alias: xb dead after q-proj; attention writes after that
    u16* pbuf = qb;   // alias: 4 x 2048x1024 bf16 partials = 16MB, dead before q-proj
    (void)xvT;

    convert_bf16<<<4096, 256, 0, stream>>>(x, xb);
    transpose_convert<<<dim3(16, 16), 256, 0, stream>>>(Wq, WqT, 1024, 1024);
    transpose_convert<<<dim3(16, 16), 256, 0, stream>>>(Wk, WkT, 1024, 1024);
    transpose_convert<<<dim3(16, 16), 256, 0, stream>>>(Wv, WvT, 1024, 1024);
    transpose_convert<<<dim3(16, 16), 256, 0, stream>>>(Wo, WoT, 1024, 1024);
    transpose_convert<<<dim3(32, 64), 256, 0, stream>>>(pk, pkT, 4096, 2048);
    transpose_convert<<<dim3(32, 64), 256, 0, stream>>>(pv, pvT, 4096, 2048);
    mask_pack<<<32768, 256, 0, stream>>>(mask, mw);

    // fused [xkT|xvT] = [WkT|WvT](M=2048) x B(xb) : [2048,8192], one launch
    gemm_nt<true, false><<<dim3(64, 16, 1), 256, 0, stream>>>(WkT, 1024, 0, xb, 1024, 0, xkT, 8192, 0, nullptr, 1024);

    // k[b] = proj_k^T @ xk[b] : split-K x2 -> bf16 partials -> combine
    gemm_nt_splitk<<<dim3(8, 16, 4), 256, 0, stream>>>(pkT, 4096, 0, xkT, 8192, 4096,
                                                       pbuf, 1024, (long long)1 << 21, 2048);
    combine_bf16<<<2048, 256, 0, stream>>>(pbuf, kbuf);
    // vT[b] = xv[b]^T @ proj_v : split-K x2
    gemm_nt_splitk<<<dim3(16, 8, 4), 256, 0, stream>>>(xvT, 8192, 4096, pvT, 4096, 0,
                                                       pbuf, 2048, (long long)1 << 21, 2048);
    combine_bf16<<<2048, 256, 0, stream>>>(pbuf, vtb);

    // q = x @ Wq (runs AFTER combines: qb overlays pbuf)
    gemm_nt<true, false><<<dim3(8, 64, 1), 256, 0, stream>>>(xb, 1024, 0, WqT, 1024, 0, qb, 1024, 0, nullptr, 1024);

    // grid (bh, qchunk): consecutive blocks differ in bh -> XCD = bh%8 (L2 locality)
    attn_kernel<<<dim3(32, 64), 256, 0, stream>>>(qb, kbuf, vtb, mw, ao);

    // out = ao @ Wo + bo (f32 out)
    gemm_nt<false, true><<<dim3(8, 64, 1), 256, 0, stream>>>(ao, 1024, 0, WoT, 1024, 0, out, 1024, 0, bo, 1024);
}

// Round 17
// 548.572 us; speedup vs baseline: 1.5909x; 1.0341x over previous
//
#include <hip/hip_runtime.h>
#include <stdint.h>

using u16 = unsigned short;
typedef __bf16 bf16x8 __attribute__((ext_vector_type(8)));
typedef float f32x4 __attribute__((ext_vector_type(4)));
typedef u16 ushort8 __attribute__((ext_vector_type(8)));
typedef unsigned uint4v __attribute__((ext_vector_type(4)));
typedef unsigned uint2v __attribute__((ext_vector_type(2)));

// ===== session ledger (do not violate) =====
// attn_kernel on this toolchain:
//  - NO __builtin_amdgcn_s_setprio around MFMA (R5/R7: absmax 2.6e28)
//  - NO __launch_bounds__ second arg (R4/R11/R12: three bodies, all corrupt)
//  - NO v_permlane16_swap (R10: wrong lane routing)
//  - NO global_load_lds under wave-divergent branches (R2/R3)
//  - NO single-barrier multi-buffer pipelines (R15: 0.359)
//  - NO >2 GLD16 per thread per barrier interval in attn (R16: 0.116)
//  => ONLY the exact R14-green shape: 2 GLD16/thread, stage(nxt); barrier;
//     process(cur); barrier. Register-only deltas permitted.
// ===========================================

__device__ __forceinline__ u16 f2bf(float f) {
    unsigned u = __builtin_bit_cast(unsigned, f);
    return (u16)((u + 0x7fffu + ((u >> 16) & 1u)) >> 16);
}

__device__ __forceinline__ float bf2f(u16 v) {
    unsigned u = (unsigned)v << 16;
    return __builtin_bit_cast(float, u);
}

__device__ __forceinline__ float fexp2(float x) {
#if __has_builtin(__builtin_amdgcn_exp2f)
    return __builtin_amdgcn_exp2f(x);
#else
    return exp2f(x);
#endif
}

__device__ __forceinline__ unsigned cvt_pk_bf16(float lo, float hi) {
    unsigned r;
    asm("v_cvt_pk_bf16_f32 %0, %1, %2" : "=v"(r) : "v"(lo), "v"(hi));
    return r;
}

// global->LDS direct copy, 16B per lane. LDS dest is wave-uniform base + lane*16.
#define GLD16(gptr, lptr) __builtin_amdgcn_global_load_lds( \
    (const __attribute__((address_space(1))) void*)(unsigned long long)(gptr), \
    (__attribute__((address_space(3))) void*)(unsigned)(unsigned long long)(lptr), 16, 0, 0)

// ---------------- conversion kernels ----------------

__global__ void convert_bf16(const float* __restrict__ in, u16* __restrict__ out) {
    int gid = blockIdx.x * 256 + threadIdx.x;      // 8 f32 per thread
    const float4* in4 = (const float4*)in;
    float4 a = in4[2 * gid], b = in4[2 * gid + 1];
    ushort8 o;
    o[0] = f2bf(a.x); o[1] = f2bf(a.y); o[2] = f2bf(a.z); o[3] = f2bf(a.w);
    o[4] = f2bf(b.x); o[5] = f2bf(b.y); o[6] = f2bf(b.z); o[7] = f2bf(b.w);
    *(ushort8*)(out + (size_t)gid * 8) = o;
}

// out[C][R] = bf16(in[R][C])  -- 64x64 LDS tile transpose
__global__ void transpose_convert(const float* __restrict__ in, u16* __restrict__ out,
                                  int R, int C) {
    __shared__ u16 sT[64][65];
    const int c0 = blockIdx.x << 6, r0 = blockIdx.y << 6;
    const int tid = threadIdx.x;
#pragma unroll
    for (int rep = 0; rep < 16; rep++) {
        int idx = rep * 256 + tid;
        int r = idx >> 6, c = idx & 63;
        sT[c][r] = f2bf(in[(size_t)(r0 + r) * C + c0 + c]);
    }
    __syncthreads();
#pragma unroll
    for (int rep = 0; rep < 16; rep++) {
        int idx = rep * 256 + tid;
        int r = idx >> 6, c = idx & 63;
        out[(size_t)(c0 + r) * R + r0 + c] = sT[r][c];
    }
}

// maskbits[i][w] bit (j&31) = (mask[i][2j+1] != 0), j = resized col index
__global__ void mask_pack(const float* __restrict__ mask, unsigned* __restrict__ mw) {
    int gid = blockIdx.x * 256 + threadIdx.x;      // 4096*2048 threads
    int i = gid >> 11, j = gid & 2047;
    float v = mask[(size_t)i * 4096 + 2 * j + 1];
    unsigned long long b = __ballot(v != 0.0f);
    int lane = threadIdx.x & 63;
    if (lane == 0)       mw[(size_t)i * 64 + (j >> 5)] = (unsigned)b;
    else if (lane == 32) mw[(size_t)i * 64 + (j >> 5)] = (unsigned)(b >> 32);
}

// ---------------- NT GEMM: C[i][j] = sum_k A[i][k]*B[j][k] ----------------
// A [M][K] row-major bf16, B [N][K] row-major bf16. 128x128 tile, BK=32, dbuf LDS.
// grid = (N/128, M/128, batches)

template <bool OUT_BF16, bool ADD_BIAS>
__global__ __launch_bounds__(256) void gemm_nt(
    const u16* __restrict__ A, int lda, long long sA,
    const u16* __restrict__ B, int ldb, long long sB,
    void* __restrict__ Cp, int ldc, long long sC,
    const float* __restrict__ bias, int K) {
    __shared__ __align__(16) u16 lds[2][2][4][128][8];   // [buf][mat][kblk][row][8] = 32KB
    const int bz = blockIdx.z;
    const u16* Ab = A + (size_t)sA * bz;
    const u16* Bb = B + (size_t)sB * bz;
    const int m0 = blockIdx.y << 7, n0 = blockIdx.x << 7;
    const int tid = threadIdx.x, wave = tid >> 6, lane = tid & 63;
    const int kg = lane >> 4, lr = lane & 15;
    const int wr = (wave >> 1) << 6, wc = (wave & 1) << 6;
    const int nT = K >> 5;
    f32x4 acc[4][4] = {};

    // prologue: stage tile 0 into buf 0. wave stages kblk==wave, rows i*64+lane.
#pragma unroll
    for (int i = 0; i < 2; i++) {
        int row = i * 64 + lane;
        GLD16(Ab + (size_t)(m0 + row) * lda + wave * 8, &lds[0][0][wave][i * 64][0]);
        GLD16(Bb + (size_t)(n0 + row) * ldb + wave * 8, &lds[0][1][wave][i * 64][0]);
    }
    for (int t = 0; t < nT; ++t) {
        const int cur = t & 1;
        if (t + 1 < nT) {
            const int nxt = cur ^ 1;
            const int koff = (t + 1) << 5;
#pragma unroll
            for (int i = 0; i < 2; i++) {
                int row = i * 64 + lane;
                GLD16(Ab + (size_t)(m0 + row) * lda + koff + wave * 8, &lds[nxt][0][wave][i * 64][0]);
                GLD16(Bb + (size_t)(n0 + row) * ldb + koff + wave * 8, &lds[nxt][1][wave][i * 64][0]);
            }
        }
        __syncthreads();   // drains vmcnt -> buf[cur] ready
        bf16x8 af[4], bfv[4];
#pragma unroll
        for (int mi = 0; mi < 4; mi++)
            af[mi] = *(const bf16x8*)&lds[cur][0][kg][wr + mi * 16 + lr][0];
#pragma unroll
        for (int ni = 0; ni < 4; ni++)
            bfv[ni] = *(const bf16x8*)&lds[cur][1][kg][wc + ni * 16 + lr][0];
#pragma unroll
        for (int mi = 0; mi < 4; mi++)
#pragma unroll
            for (int ni = 0; ni < 4; ni++)
                acc[mi][ni] = __builtin_amdgcn_mfma_f32_16x16x32_bf16(af[mi], bfv[ni], acc[mi][ni], 0, 0, 0);
        __syncthreads();   // all reads of buf[cur] done before it is re-staged
    }

    if constexpr (OUT_BF16) {
        u16* C = (u16*)Cp + (size_t)sC * bz;
#pragma unroll
        for (int mi = 0; mi < 4; mi++)
#pragma unroll
            for (int ni = 0; ni < 4; ni++)
#pragma unroll
                for (int r = 0; r < 4; r++) {
                    int gr = m0 + wr + mi * 16 + kg * 4 + r;
                    int gc = n0 + wc + ni * 16 + lr;
                    C[(size_t)gr * ldc + gc] = f2bf(acc[mi][ni][r]);
                }
    } else {
        float* C = (float*)Cp + (size_t)sC * bz;
#pragma unroll
        for (int mi = 0; mi < 4; mi++)
#pragma unroll
            for (int ni = 0; ni < 4; ni++)
#pragma unroll
                for (int r = 0; r < 4; r++) {
                    int gr = m0 + wr + mi * 16 + kg * 4 + r;
                    int gc = n0 + wc + ni * 16 + lr;
                    float v = acc[mi][ni][r];
                    if constexpr (ADD_BIAS) v += bias[gc];
                    C[(size_t)gr * ldc + gc] = v;
                }
    }
}

// ---- split-K variant: bz in [0,4) = (bsel = bz>>1, ks = bz&1). bf16 partials.
// Cpart[bz][i][j] = sum_{k in half ks} A[bsel-slice][i][k] * B[bsel-slice][j][k]
__global__ __launch_bounds__(256) void gemm_nt_splitk(
    const u16* __restrict__ A, int lda, long long sAb,
    const u16* __restrict__ B, int ldb, long long sBb,
    u16* __restrict__ Cp, int ldc, long long sC, int K2) {
    __shared__ __align__(16) u16 lds[2][2][4][128][8];
    const int bz = blockIdx.z, bsel = bz >> 1, ks = bz & 1;
    const u16* Ab = A + (size_t)sAb * bsel + (size_t)ks * K2;
    const u16* Bb = B + (size_t)sBb * bsel + (size_t)ks * K2;
    const int m0 = blockIdx.y << 7, n0 = blockIdx.x << 7;
    const int tid = threadIdx.x, wave = tid >> 6, lane = tid & 63;
    const int kg = lane >> 4, lr = lane & 15;
    const int wr = (wave >> 1) << 6, wc = (wave & 1) << 6;
    const int nT = K2 >> 5;
    f32x4 acc[4][4] = {};

#pragma unroll
    for (int i = 0; i < 2; i++) {
        int row = i * 64 + lane;
        GLD16(Ab + (size_t)(m0 + row) * lda + wave * 8, &lds[0][0][wave][i * 64][0]);
        GLD16(Bb + (size_t)(n0 + row) * ldb + wave * 8, &lds[0][1][wave][i * 64][0]);
    }
    for (int t = 0; t < nT; ++t) {
        const int cur = t & 1;
        if (t + 1 < nT) {
            const int nxt = cur ^ 1;
            const int koff = (t + 1) << 5;
#pragma unroll
            for (int i = 0; i < 2; i++) {
                int row = i * 64 + lane;
                GLD16(Ab + (size_t)(m0 + row) * lda + koff + wave * 8, &lds[nxt][0][wave][i * 64][0]);
                GLD16(Bb + (size_t)(n0 + row) * ldb + koff + wave * 8, &lds[nxt][1][wave][i * 64][0]);
            }
        }
        __syncthreads();
        bf16x8 af[4], bfv[4];
#pragma unroll
        for (int mi = 0; mi < 4; mi++)
            af[mi] = *(const bf16x8*)&lds[cur][0][kg][wr + mi * 16 + lr][0];
#pragma unroll
        for (int ni = 0; ni < 4; ni++)
            bfv[ni] = *(const bf16x8*)&lds[cur][1][kg][wc + ni * 16 + lr][0];
#pragma unroll
        for (int mi = 0; mi < 4; mi++)
#pragma unroll
            for (int ni = 0; ni < 4; ni++)
                acc[mi][ni] = __builtin_amdgcn_mfma_f32_16x16x32_bf16(af[mi], bfv[ni], acc[mi][ni], 0, 0, 0);
        __syncthreads();
    }

    u16* C = Cp + (size_t)sC * bz;
#pragma unroll
    for (int mi = 0; mi < 4; mi++)
#pragma unroll
        for (int ni = 0; ni < 4; ni++)
#pragma unroll
            for (int r = 0; r < 4; r++) {
                int gr = m0 + wr + mi * 16 + kg * 4 + r;
                int gc = n0 + wc + ni * 16 + lr;
                C[(size_t)gr * ldc + gc] = f2bf(acc[mi][ni][r]);
            }
}

// dst[d] = bf16( p[(2b)S + r] + p[(2b+1)S + r] ),  d = b*S + r, S = 2^21
__global__ void combine_bf16(const u16* __restrict__ p, u16* __restrict__ dst) {
    int gid = blockIdx.x * 256 + threadIdx.x;   // 524288 threads, 8 elems each
    size_t d = (size_t)gid * 8;
    size_t b = d >> 21, r = d & (((size_t)1 << 21) - 1);
    const ushort8 a = *(const ushort8*)(p + ((b * 2) << 21) + r);
    const ushort8 c = *(const ushort8*)(p + ((b * 2 + 1) << 21) + r);
    ushort8 o;
#pragma unroll
    for (int i = 0; i < 8; i++) o[i] = f2bf(bf2f(a[i]) + bf2f(c[i]));
    *(ushort8*)(dst + d) = o;
}

// ---------------- flash attention over compressed K/V (R14-green + mask prefetch)
// Per wave: 16 q rows (q = nrow+lr), loop kp tiles of 32. Structure is the
// EXACT R14-green shape (2 GLD16/thread; stage(nxt); barrier; process; barrier).
// SOLE delta vs R14: the mask word for tile t+1 is loaded BEFORE the barrier
// (plain register global load, compiler-modeled) so its ~200cy L2 latency
// overlaps the stage drain instead of sitting serially after the barrier.

__global__ __launch_bounds__(256) void attn_kernel(
    const u16* __restrict__ q, const u16* __restrict__ kb,
    const u16* __restrict__ vt, const unsigned* __restrict__ mw,
    u16* __restrict__ ao) {
    __shared__ __align__(16) u16 sK[2][8][32][8];   // [buf][dh8][kp][8] 4KB/buf
    __shared__ __align__(16) u16 sV[2][4][64][8];   // [buf][kp8][dh][8] 4KB/buf
    const int tid = threadIdx.x;
    const int wave = tid >> 6, lane = tid & 63, kg = lane >> 4, lr = lane & 15;
    const int b = blockIdx.x >> 4, h = blockIdx.x & 15;
    const int nrow = (blockIdx.y << 6) + wave * 16;

    const u16* qrow = q + (size_t)(b * 4096 + nrow + lr) * 1024 + h * 64 + kg * 8;
    const bf16x8 aq0 = *(const bf16x8*)qrow;
    const bf16x8 aq1 = *(const bf16x8*)(qrow + 32);
    const u16* kh = kb + (size_t)b * 2048 * 1024 + h * 64;
    const u16* vh = vt + ((size_t)b * 1024 + (size_t)h * 64) * 2048;
    const unsigned* mrow = mw + (size_t)(nrow + lr) * 64;

    // branch-free staging addresses (fixed per thread; only j0 varies)
    const u16* ksrc = kh + (size_t)(lane & 31) * 1024 + (wave * 2 + (lane >> 5)) * 8;
    const u16* vsrc = vh + (size_t)lane * 2048 + wave * 8;

    f32x4 o[4] = {};      // o[f][r] = O[q=lr][dh = f*16 + kg*4 + r] (unnormalized)
    float lsum = 0.0f;
    const bool low16 = (lane & 16) == 0;

    auto stage = [&](int bf, int j0) {
        GLD16(ksrc + (size_t)j0 * 1024, &sK[bf][wave * 2][0][0]);
        GLD16(vsrc + j0, &sV[bf][wave][0][0]);
    };

    auto process = [&](int cur, unsigned wd) {
        const bf16x8 k0a = *(const bf16x8*)&sK[cur][kg][lr][0];
        const bf16x8 k0b = *(const bf16x8*)&sK[cur][4 + kg][lr][0];
        const bf16x8 k1a = *(const bf16x8*)&sK[cur][kg][16 + lr][0];
        const bf16x8 k1b = *(const bf16x8*)&sK[cur][4 + kg][16 + lr][0];
        const bf16x8 v0 = *(const bf16x8*)&sV[cur][kg][lr][0];
        const bf16x8 v1 = *(const bf16x8*)&sV[cur][kg][16 + lr][0];
        const bf16x8 v2 = *(const bf16x8*)&sV[cur][kg][32 + lr][0];
        const bf16x8 v3 = *(const bf16x8*)&sV[cur][kg][48 + lr][0];

        f32x4 s0 = {0.f, 0.f, 0.f, 0.f}, s1 = {0.f, 0.f, 0.f, 0.f};
        s0 = __builtin_amdgcn_mfma_f32_16x16x32_bf16(k0a, aq0, s0, 0, 0, 0);
        s0 = __builtin_amdgcn_mfma_f32_16x16x32_bf16(k0b, aq1, s0, 0, 0, 0);
        s1 = __builtin_amdgcn_mfma_f32_16x16x32_bf16(k1a, aq0, s1, 0, 0, 0);
        s1 = __builtin_amdgcn_mfma_f32_16x16x32_bf16(k1b, aq1, s1, 0, 0, 0);
        const unsigned mb0 = wd >> (kg * 4);
        const unsigned mb1 = wd >> (16 + kg * 4);
        // p = exp2(s * (0.125*log2e)); masked -> 0
        const float C = 0.18033688f;
        float p0[4], p1[4];
#pragma unroll
        for (int r = 0; r < 4; r++) {
            float t0 = ((mb0 >> r) & 1u) ? -1.0e30f : s0[r] * C;
            float t1 = ((mb1 >> r) & 1u) ? -1.0e30f : s1[r] * C;
            p0[r] = fexp2(t0);
            p1[r] = fexp2(t1);
            lsum += p0[r] + p1[r];
        }
        // pack to bf16 pairs: c* hold kp kg*4+{01,23}, d* hold kp 16+kg*4+{01,23}
        unsigned X0 = cvt_pk_bf16(p0[0], p0[1]);
        unsigned X1 = cvt_pk_bf16(p0[2], p0[3]);
        unsigned Y0 = cvt_pk_bf16(p1[0], p1[1]);
        unsigned Y1 = cvt_pk_bf16(p1[2], p1[3]);
        // lane-transpose P^T -> B-frag (lane needs kp slice kg*8..kg*8+7 for q=lr)
        asm volatile("v_permlane32_swap_b32 %0, %1" : "+v"(X0), "+v"(Y0));
        asm volatile("v_permlane32_swap_b32 %0, %1" : "+v"(X1), "+v"(Y1));
        unsigned sX0 = (unsigned)__shfl_xor((int)X0, 16);
        unsigned sY0 = (unsigned)__shfl_xor((int)Y0, 16);
        unsigned sX1 = (unsigned)__shfl_xor((int)X1, 16);
        unsigned sY1 = (unsigned)__shfl_xor((int)Y1, 16);
        uint4v wv;
        wv[0] = low16 ? X0 : sY0;
        wv[1] = low16 ? X1 : sY1;
        wv[2] = low16 ? sX0 : Y0;
        wv[3] = low16 ? sX1 : Y1;
        bf16x8 W = __builtin_bit_cast(bf16x8, wv);
        o[0] = __builtin_amdgcn_mfma_f32_16x16x32_bf16(v0, W, o[0], 0, 0, 0);
        o[1] = __builtin_amdgcn_mfma_f32_16x16x32_bf16(v1, W, o[1], 0, 0, 0);
        o[2] = __builtin_amdgcn_mfma_f32_16x16x32_bf16(v2, W, o[2], 0, 0, 0);
        o[3] = __builtin_amdgcn_mfma_f32_16x16x32_bf16(v3, W, o[3], 0, 0, 0);
    };

    stage(0, 0);
    unsigned wdc = mrow[0];
    for (int t = 0; t < 64; ++t) {
        const int cur = t & 1;
        if (t < 63) stage(cur ^ 1, (t + 1) * 32);
        unsigned wdn = (t < 63) ? mrow[t + 1] : 0u;   // prefetch next mask word
        __syncthreads();   // drains vmcnt -> buf[cur] ready (and wdn)
        process(cur, wdc);
        wdc = wdn;
        __syncthreads();   // all reads of buf[cur] done before re-stage
    }

    lsum += __shfl_xor(lsum, 16);
    lsum += __shfl_xor(lsum, 32);
    const float inv = 1.0f / lsum;

    u16* orow = ao + (size_t)(b * 4096 + nrow + lr) * 1024 + h * 64 + kg * 4;
#pragma unroll
    for (int f = 0; f < 4; f++) {
        uint2v st;
        st[0] = cvt_pk_bf16(o[f][0] * inv, o[f][1] * inv);
        st[1] = cvt_pk_bf16(o[f][2] * inv, o[f][3] * inv);
        *(uint2v*)(orow + f * 16) = st;
    }
}

// ---------------- launcher ----------------

extern "C" void kernel_launch(void* const* d_in, const int* in_sizes, int n_in,
                              void* d_out, int out_size, void* d_ws, size_t ws_size,
                              hipStream_t stream) {
    const float* x    = (const float*)d_in[0];
    const float* mask = (const float*)d_in[1];
    const float* Wq   = (const float*)d_in[2];
    const float* Wk   = (const float*)d_in[3];
    const float* Wv   = (const float*)d_in[4];
    const float* Wo   = (const float*)d_in[5];
    const float* bo   = (const float*)d_in[6];
    const float* pk   = (const float*)d_in[7];
    const float* pv   = (const float*)d_in[8];
    float* out = (float*)d_out;

    char* w = (char*)d_ws;
    auto alloc = [&](size_t bytes) { void* p = w; w += (bytes + 255) & ~(size_t)255; return p; };
    u16* xb   = (u16*)alloc((size_t)8192 * 1024 * 2);
    u16* qb   = (u16*)alloc((size_t)8192 * 1024 * 2);
    u16* xkT  = (u16*)alloc((size_t)1024 * 8192 * 2);   // [xkT|xvT] contiguous:
    u16* xvT  = (u16*)alloc((size_t)1024 * 8192 * 2);   // fused M=2048 GEMM output
    u16* WqT  = (u16*)alloc((size_t)1024 * 1024 * 2);
    u16* WkT  = (u16*)alloc((size_t)1024 * 1024 * 2);   // [WkT|WvT] contiguous:
    u16* WvT  = (u16*)alloc((size_t)1024 * 1024 * 2);   // fused GEMM A-operand
    u16* WoT  = (u16*)alloc((size_t)1024 * 1024 * 2);
    u16* pkT  = (u16*)alloc((size_t)2048 * 4096 * 2);
    u16* pvT  = (u16*)alloc((size_t)2048 * 4096 * 2);
    u16* kbuf = (u16*)alloc((size_t)2 * 2048 * 1024 * 2);
    u16* vtb  = (u16*)alloc((size_t)2 * 1024 * 2048 * 2);
    unsigned* mw = (unsigned*)alloc((size_t)4096 * 64 * 4);
    (void)alloc((size_t)128 * 1024);   // guard pad
    u16* ao   = xb;   // alias: xb dead after q-proj; attention writes after that
    u16* pbuf = qb;   // alias: 4 x 2048x1024 bf16 partials = 16MB, dead before q-proj
    (void)xvT;

    convert_bf16<<<4096, 256, 0, stream>>>(x, xb);
    transpose_convert<<<dim3(16, 16), 256, 0, stream>>>(Wq, WqT, 1024, 1024);
    transpose_convert<<<dim3(16, 16), 256, 0, stream>>>(Wk, WkT, 1024, 1024);
    transpose_convert<<<dim3(16, 16), 256, 0, stream>>>(Wv, WvT, 1024, 1024);
    transpose_convert<<<dim3(16, 16), 256, 0, stream>>>(Wo, WoT, 1024, 1024);
    transpose_convert<<<dim3(32, 64), 256, 0, stream>>>(pk, pkT, 4096, 2048);
    transpose_convert<<<dim3(32, 64), 256, 0, stream>>>(pv, pvT, 4096, 2048);
    mask_pack<<<32768, 256, 0, stream>>>(mask, mw);

    // fused [xkT|xvT] = [WkT|WvT](M=2048) x B(xb) : [2048,8192], one launch
    gemm_nt<true, false><<<dim3(64, 16, 1), 256, 0, stream>>>(WkT, 1024, 0, xb, 1024, 0, xkT, 8192, 0, nullptr, 1024);

    // k[b] = proj_k^T @ xk[b] : split-K x2 -> bf16 partials -> combine
    gemm_nt_splitk<<<dim3(8, 16, 4), 256, 0, stream>>>(pkT, 4096, 0, xkT, 8192, 4096,
                                                       pbuf, 1024, (long long)1 << 21, 2048);
    combine_bf16<<<2048, 256, 0, stream>>>(pbuf, kbuf);
    // vT[b] = xv[b]^T @ proj_v : split-K x2
    gemm_nt_splitk<<<dim3(16, 8, 4), 256, 0, stream>>>(xvT, 8192, 4096, pvT, 4096, 0,
                                                       pbuf, 2048, (long long)1 << 21, 2048);
    combine_bf16<<<2048, 256, 0, stream>>>(pbuf, vtb);

    // q = x @ Wq (runs AFTER combines: qb overlays pbuf)
    gemm_nt<true, false><<<dim3(8, 64, 1), 256, 0, stream>>>(xb, 1024, 0, WqT, 1024, 0, qb, 1024, 0, nullptr, 1024);

    // grid (bh, qchunk): consecutive blocks differ in bh -> XCD = bh%8 (L2 locality)
    attn_kernel<<<dim3(32, 64), 256, 0, stream>>>(qb, kbuf, vtb, mw, ao);

    // out = ao @ Wo + bo (f32 out)
    gemm_nt<false, true><<<dim3(8, 64, 1), 256, 0, stream>>>(ao, 1024, 0, WoT, 1024, 0, out, 1024, 0, bo, 1024);
}